// Round 13
// baseline (900.968 us; speedup 1.0000x reference)
//
#include <hip/hip_runtime.h>
#include <hip/hip_bf16.h>
#include <cstdint>
#include <cstddef>

#define EMBED  1024
#define NEXP   8
#define HIDDEN 4096
#define TOKENS 4096
#define MC     1024   // gemm1 token chunk (R3-measured 80 us/chunk regime)

typedef __attribute__((ext_vector_type(8))) short bf16x8;
typedef __attribute__((ext_vector_type(4))) float f32x4;
using bf16 = __hip_bfloat16;

// ---------------- async global->LDS (16B per lane) ----------------
__device__ __forceinline__ void gload_lds16(const void* g, void* l) {
    __builtin_amdgcn_global_load_lds((const __attribute__((address_space(1))) void*)g,
                                     (__attribute__((address_space(3))) void*)l,
                                     16, 0, 0);
}

// LDS swizzle for gemm2 [*][128B] tiles (involution; 0 conflicts measured R7-R12)
__device__ __forceinline__ int swzB(int b) { return b ^ (((b >> 7) & 7) << 4); }

// ---------------- fp32 -> bf16 elementwise convert ----------------
__global__ void cvt_kernel(const float* __restrict__ in, bf16* __restrict__ out, size_t n) {
    size_t i = ((size_t)blockIdx.x * blockDim.x + threadIdx.x) * 4;
    if (i + 3 < n) {
        float4 v = *(const float4*)(in + i);
        out[i + 0] = __float2bfloat16(v.x);
        out[i + 1] = __float2bfloat16(v.y);
        out[i + 2] = __float2bfloat16(v.z);
        out[i + 3] = __float2bfloat16(v.w);
    }
}

// ------------- transpose + convert: out[e][n][k] = in[e][k][n] -------------
__global__ void transpose_cvt(const float* __restrict__ in, bf16* __restrict__ out,
                              int K, int N, size_t in_estride, size_t out_eoff, int ldo) {
    const int e = blockIdx.z;
    const float* ine = in + (size_t)e * in_estride;
    bf16* oute = out + (size_t)e * out_eoff;
    __shared__ float tile[32][33];
    const int n0 = blockIdx.x * 32, k0 = blockIdx.y * 32;
    const int tx = threadIdx.x, ty = threadIdx.y;
    #pragma unroll
    for (int i = ty; i < 32; i += 8)
        tile[i][tx] = ine[(size_t)(k0 + i) * N + n0 + tx];
    __syncthreads();
    #pragma unroll
    for (int i = ty; i < 32; i += 8)
        oute[(size_t)(n0 + i) * ldo + k0 + tx] = __float2bfloat16(tile[tx][i]);
}

// ---------------- router: per-token top-2 masked softmax ----------------
__global__ void router_kernel(const float* __restrict__ x, const float* __restrict__ Wr,
                              const float* __restrict__ br, float* __restrict__ w) {
    const int t = blockIdx.x;
    const int lane = threadIdx.x;  // 64 threads
    const float* xt = x + (size_t)t * EMBED;
    float s[NEXP];
    #pragma unroll
    for (int e = 0; e < NEXP; e++) s[e] = 0.f;
    for (int k = lane; k < EMBED; k += 64) {
        const float xv = xt[k];
        const float* wrk = Wr + (size_t)k * NEXP;
        #pragma unroll
        for (int e = 0; e < NEXP; e++) s[e] = fmaf(xv, wrk[e], s[e]);
    }
    #pragma unroll
    for (int e = 0; e < NEXP; e++) {
        #pragma unroll
        for (int off = 32; off >= 1; off >>= 1)
            s[e] += __shfl_xor(s[e], off);
    }
    if (lane == 0) {
        float sc[NEXP];
        #pragma unroll
        for (int e = 0; e < NEXP; e++) sc[e] = s[e] + br[e];
        int i1 = 0; float m1 = sc[0];
        #pragma unroll
        for (int e = 1; e < NEXP; e++) if (sc[e] > m1) { m1 = sc[e]; i1 = e; }
        int i2 = -1; float m2 = -1e30f;
        #pragma unroll
        for (int e = 0; e < NEXP; e++) if (e != i1 && sc[e] > m2) { m2 = sc[e]; i2 = e; }
        const float mx = fmaxf(m1, 0.f);
        const float denom = 6.f * expf(0.f - mx) + expf(m1 - mx) + expf(m2 - mx);
        #pragma unroll
        for (int e = 0; e < NEXP; e++) {
            float v = (e == i1) ? m1 : ((e == i2) ? m2 : 0.f);
            w[(size_t)t * NEXP + e] = expf(v - mx) / denom;
        }
    }
}

// ======== GEMM1: R3-verbatim 1-phase 128^2, chunked M (measured 80 us/chunk) ========
// Grid (HIDDEN/128=32, MC/128=8, 8): bcol fastest -> B-panel swept while A-slab (2MB)
// stays L2/L3-hot; hbuf chunk-contiguous [e][MC][HIDDEN].
__global__ __launch_bounds__(256) void gemm1(const bf16* __restrict__ A,   // x chunk [MC][EMBED]
                                             const bf16* __restrict__ Bt,  // w1t [e][HIDDEN][EMBED]
                                             const float* __restrict__ b1,
                                             const float* __restrict__ rw, // chunk [MC][8]
                                             bf16* __restrict__ H) {       // chunk [e][MC][HIDDEN]
    const int e = blockIdx.z;
    const int brow = blockIdx.y * 128;
    const int bcol = blockIdx.x * 128;
    const bf16* Be = Bt + (size_t)e * HIDDEN * EMBED;
    bf16* He = H + (size_t)e * MC * HIDDEN;
    __shared__ __align__(16) bf16 As[128 * 32];
    __shared__ __align__(16) bf16 Bs[128 * 32];
    const int tid = threadIdx.x;
    f32x4 acc[4][4] = {};

    const int seg0 = tid, seg1 = tid + 256;
    const int r0 = seg0 >> 2, c0 = seg0 & 3;
    const int r1 = seg1 >> 2, c1 = seg1 & 3;
    const bf16* ga0 = A + (size_t)(brow + r0) * EMBED + c0 * 8;
    const bf16* ga1 = A + (size_t)(brow + r1) * EMBED + c1 * 8;
    const bf16* gb0 = Be + (size_t)(bcol + r0) * EMBED + c0 * 8;
    const bf16* gb1 = Be + (size_t)(bcol + r1) * EMBED + c1 * 8;

    const int lane = tid & 63, wid = tid >> 6;
    const int wv_r = (wid >> 1) * 64, wv_c = (wid & 1) * 64;
    const int fr = lane & 15, kb = (lane >> 4) * 8;

    for (int kt = 0; kt < EMBED; kt += 32) {
        gload_lds16(ga0 + kt, As + seg0 * 8);
        gload_lds16(ga1 + kt, As + seg1 * 8);
        gload_lds16(gb0 + kt, Bs + seg0 * 8);
        gload_lds16(gb1 + kt, Bs + seg1 * 8);
        __syncthreads();
        bf16x8 af[4], bfr[4];
        #pragma unroll
        for (int m = 0; m < 4; m++) af[m] = *(const bf16x8*)&As[(wv_r + m * 16 + fr) * 32 + kb];
        #pragma unroll
        for (int n = 0; n < 4; n++) bfr[n] = *(const bf16x8*)&Bs[(wv_c + n * 16 + fr) * 32 + kb];
        #pragma unroll
        for (int m = 0; m < 4; m++)
            #pragma unroll
            for (int n = 0; n < 4; n++)
                acc[m][n] = __builtin_amdgcn_mfma_f32_16x16x32_bf16(af[m], bfr[n], acc[m][n], 0, 0, 0);
        __syncthreads();
    }

    #pragma unroll
    for (int n = 0; n < 4; n++) {
        const int col = bcol + wv_c + n * 16 + fr;
        const float bias = b1[e * HIDDEN + col];
        #pragma unroll
        for (int m = 0; m < 4; m++) {
            const int rowb = brow + wv_r + m * 16 + (lane >> 4) * 4;
            #pragma unroll
            for (int j = 0; j < 4; j++) {
                const int row = rowb + j;
                float v = acc[m][n][j] + bias;
                v = fmaxf(v, 0.f) * rw[(size_t)row * NEXP + e];
                He[(size_t)row * HIDDEN + col] = __float2bfloat16(v);
            }
        }
    }
}

// ======== GEMM2: R12-verbatim 256^2 8-wave rebalanced pipeline, 2 experts/block ========
// Grid (4, 16, 4) = 256 blocks = 1/CU. A layout now [chunk][e][MC][HIDDEN].
#define BARX()  { __builtin_amdgcn_sched_barrier(0); __builtin_amdgcn_s_barrier(); __builtin_amdgcn_sched_barrier(0); }
#define LGKM0() { asm volatile("s_waitcnt lgkmcnt(0)" ::: "memory"); __builtin_amdgcn_sched_barrier(0); }

// K-element offset of K-tile T (64 bf16 per tile), crossing into expert+1 at T=64:
#define KOFF(T, estride) ((size_t)((T) & 63) * 64 + (size_t)((T) >> 6) * (estride))

#define PIPE_PREAMBLE(Abase, Bbase, lda, ldb)                                        \
    __shared__ __align__(16) bf16 As[2][2][128 * 64];                                \
    __shared__ __align__(16) bf16 Bs[2][2][128 * 64];                                \
    const int tid = threadIdx.x;                                                     \
    const int lane = tid & 63, wid = tid >> 6;                                       \
    const int mhalf = wid >> 2, wB = wid & 3;                                        \
    const int nhalf = wB >> 1, nsub = wB & 1;                                        \
    const int wv_r = mhalf * 128, wv_c = wB * 64;                                    \
    f32x4 acc[8][4] = {};                                                            \
    int rowloc[2], colel[2];                                                         \
    _Pragma("unroll")                                                                \
    for (int j = 0; j < 2; j++) {                                                    \
        int bs = swzB(tid * 16 + j * 8192);                                          \
        rowloc[j] = bs >> 7; colel[j] = (bs & 127) >> 1;                             \
    }                                                                                \
    const bf16* pA0 = (Abase) + (size_t)(brow + rowloc[0]) * (lda) + colel[0];       \
    const bf16* pA1 = (Abase) + (size_t)(brow + rowloc[1]) * (lda) + colel[1];       \
    const bf16* pB0 = (Bbase) + (size_t)(bcol + rowloc[0]) * (ldb) + colel[0];       \
    const bf16* pB1 = (Bbase) + (size_t)(bcol + rowloc[1]) * (ldb) + colel[1];       \
    const int fr = lane & 15, kb0 = (lane >> 4) * 16;                                \
    const int xm = (fr & 7) << 4;                                                    \
    const int baA0 = (fr * 128 + kb0) ^ xm, baA1 = (fr * 128 + kb0 + 64) ^ xm;       \
    const int brB = (nsub * 64 + fr) * 128;                                          \
    const int baB0 = (brB + kb0) ^ xm, baB1 = (brB + kb0 + 64) ^ xm;

#define STAGE_A(bi, h, koff, lda)                                                    \
    do {                                                                             \
        gload_lds16(pA0 + (size_t)(h) * 128 * (lda) + (koff), &As[bi][h][tid * 8]);  \
        gload_lds16(pA1 + (size_t)(h) * 128 * (lda) + (koff), &As[bi][h][tid * 8 + 4096]); \
    } while (0)
#define STAGE_B(bi, h, koff, ldb)                                                    \
    do {                                                                             \
        gload_lds16(pB0 + (size_t)(h) * 128 * (ldb) + (koff), &Bs[bi][h][tid * 8]);  \
        gload_lds16(pB1 + (size_t)(h) * 128 * (ldb) + (koff), &Bs[bi][h][tid * 8 + 4096]); \
    } while (0)

#define MFMA_Q(mh, nh)                                                               \
    __builtin_amdgcn_s_setprio(1);                                                   \
    _Pragma("unroll")                                                                \
    for (int mm = 0; mm < 4; mm++)                                                   \
        _Pragma("unroll")                                                            \
        for (int nn = 0; nn < 2; nn++) {                                             \
            acc[(mh)*4+mm][(nh)*2+nn] = __builtin_amdgcn_mfma_f32_16x16x32_bf16(     \
                a[(mh)*4+mm][0], b[(nh)*2+nn][0], acc[(mh)*4+mm][(nh)*2+nn], 0,0,0); \
            acc[(mh)*4+mm][(nh)*2+nn] = __builtin_amdgcn_mfma_f32_16x16x32_bf16(     \
                a[(mh)*4+mm][1], b[(nh)*2+nn][1], acc[(mh)*4+mm][(nh)*2+nn], 0,0,0); \
        }                                                                            \
    __builtin_amdgcn_s_setprio(0);

#define PIPE_KLOOP(NT, lda, ldb, eA, eB)                                             \
    STAGE_A(0, 0, 0, lda); STAGE_A(0, 1, 0, lda);                                    \
    STAGE_B(0, 0, 0, ldb); STAGE_B(0, 1, 0, ldb);                                    \
    STAGE_A(1, 0, 64, lda); STAGE_A(1, 1, 64, lda);                                  \
    STAGE_B(1, 0, 64, ldb); STAGE_B(1, 1, 64, ldb);                                  \
    asm volatile("s_waitcnt vmcnt(8)" ::: "memory");                                 \
    BARX();                                                                          \
    for (int t = 0; t < (NT); ++t) {                                                 \
        const int bi = t & 1;                                                        \
        const bool st = (t + 2) < (NT);                                              \
        const size_t koffA = KOFF(t + 2, eA);                                        \
        const size_t koffB = KOFF(t + 2, eB);                                        \
        const char* Ah = (const char*)&As[bi][mhalf][0];                             \
        const char* Bh = (const char*)&Bs[bi][nhalf][0];                             \
        bf16x8 a[8][2], b[4][2];                                                     \
        /* PH1: read a0-3 (8) + b0-1 (4) -> Q(0,0) */                                \
        _Pragma("unroll")                                                            \
        for (int m = 0; m < 4; m++) {                                                \
            a[m][0] = *(const bf16x8*)(Ah + baA0 + m * 2048);                        \
            a[m][1] = *(const bf16x8*)(Ah + baA1 + m * 2048);                        \
        }                                                                            \
        _Pragma("unroll")                                                            \
        for (int n = 0; n < 2; n++) {                                                \
            b[n][0] = *(const bf16x8*)(Bh + baB0 + n * 2048);                        \
            b[n][1] = *(const bf16x8*)(Bh + baB1 + n * 2048);                        \
        }                                                                            \
        BARX(); LGKM0();                                                             \
        MFMA_Q(0, 0)                                                                 \
        /* PH2: read b2-3 (4) -> Q(0,1) */                                           \
        _Pragma("unroll")                                                            \
        for (int n = 2; n < 4; n++) {                                                \
            b[n][0] = *(const bf16x8*)(Bh + baB0 + n * 2048);                        \
            b[n][1] = *(const bf16x8*)(Bh + baB1 + n * 2048);                        \
        }                                                                            \
        BARX(); LGKM0();                                                             \
        MFMA_Q(0, 1)                                                                 \
        BARX();                                                                      \
        /* PH3: read a4-7 (8); stage B(t+2) -> Q(1,0) */                             \
        _Pragma("unroll")                                                            \
        for (int m = 4; m < 8; m++) {                                                \
            a[m][0] = *(const bf16x8*)(Ah + baA0 + m * 2048);                        \
            a[m][1] = *(const bf16x8*)(Ah + baA1 + m * 2048);                        \
        }                                                                            \
        if (st) { STAGE_B(bi, 0, koffB, ldb); STAGE_B(bi, 1, koffB, ldb); }          \
        BARX(); LGKM0();                                                             \
        MFMA_Q(1, 0)                                                                 \
        BARX();                                                                      \
        /* PH4: stage A(t+2); Q(1,1); counted vmcnt drains t+1 only */               \
        if (st) { STAGE_A(bi, 0, koffA, lda); STAGE_A(bi, 1, koffA, lda); }          \
        MFMA_Q(1, 1)                                                                 \
        if (st) { asm volatile("s_waitcnt vmcnt(8)" ::: "memory"); }                 \
        else    { asm volatile("s_waitcnt vmcnt(0)" ::: "memory"); }                 \
        BARX();                                                                      \
    }

// out = Sum_e h'_e @ W2_e (+ Sum_e w*b2). kc = expert pair {2kc, 2kc+1}.
// A layout [chunk][e][MC][HIDDEN]; 256-row tiles never straddle chunks (1024%256==0).
__global__ __launch_bounds__(512, 2) void gemm2(const bf16* __restrict__ A,
                                                const bf16* __restrict__ Bt,  // w2t [e][EMBED][HIDDEN]
                                                const float* __restrict__ b2, // [NEXP][EMBED]
                                                const float* __restrict__ rw, // [M][8]
                                                float* __restrict__ out) {    // [M][EMBED]
    const int kc = blockIdx.z;            // 0..3 -> experts 2kc, 2kc+1
    const int brow_g = blockIdx.y * 256;  // global token row
    const int bcol = blockIdx.x * 256;
    const size_t eAc = (size_t)MC * HIDDEN;            // expert stride within chunk
    const size_t CHST = (size_t)NEXP * MC * HIDDEN;    // chunk stride
    const size_t eB = (size_t)EMBED * HIDDEN;          // expert stride in B
    const bf16* Ae = A + (size_t)(brow_g >> 10) * CHST + (size_t)(kc * 2) * eAc;
    const bf16* Be = Bt + (size_t)(kc * 2) * eB;
    const int brow = brow_g & (MC - 1);   // chunk-local row for A addressing

    PIPE_PREAMBLE(Ae, Be, HIDDEN, HIDDEN)
    PIPE_KLOOP(128, HIDDEN, HIDDEN, eAc, eB)

    #pragma unroll
    for (int n = 0; n < 4; n++) {
        const int col = bcol + wv_c + n * 16 + fr;
        #pragma unroll
        for (int m = 0; m < 8; m++) {
            const int rowb = brow_g + wv_r + m * 16 + (lane >> 4) * 4;
            #pragma unroll
            for (int j = 0; j < 4; j++) {
                const int row = rowb + j;
                float v = acc[m][n][j];
                if (kc == 0) {
                    const float* wrow = rw + (size_t)row * NEXP;
                    float s = 0.f;
                    #pragma unroll
                    for (int ee = 0; ee < NEXP; ee++) s = fmaf(wrow[ee], b2[ee * EMBED + col], s);
                    v += s;
                }
                atomicAdd(out + (size_t)row * EMBED + col, v);
            }
        }
    }
}

extern "C" void kernel_launch(void* const* d_in, const int* in_sizes, int n_in,
                              void* d_out, int out_size, void* d_ws, size_t ws_size,
                              hipStream_t stream) {
    const float* x  = (const float*)d_in[0];
    const float* W1 = (const float*)d_in[1];
    const float* b1 = (const float*)d_in[2];
    const float* W2 = (const float*)d_in[3];
    const float* b2 = (const float*)d_in[4];
    const float* Wr = (const float*)d_in[5];
    const float* br = (const float*)d_in[6];
    float* out = (float*)d_out;

    uint8_t* ws = (uint8_t*)d_ws;
    size_t off = 0;
    auto walloc = [&](size_t bytes) -> void* {
        void* p = ws + off;
        off += (bytes + 255) & ~(size_t)255;
        return p;
    };
    float* rw  = (float*)walloc((size_t)TOKENS * NEXP * 4);
    bf16* xb   = (bf16*)walloc((size_t)TOKENS * EMBED * 2);
    bf16* w1t  = (bf16*)walloc((size_t)NEXP * HIDDEN * EMBED * 2);
    bf16* w2t  = (bf16*)walloc((size_t)NEXP * EMBED * HIDDEN * 2);
    bf16* hbuf = (bf16*)walloc((size_t)NEXP * TOKENS * HIDDEN * 2);  // 256 MB, [chunk][e][MC][H]

    hipMemsetAsync(d_out, 0, (size_t)out_size * sizeof(float), stream);

    cvt_kernel<<<4096, 256, 0, stream>>>(x, xb, (size_t)TOKENS * EMBED);

    dim3 tb(32, 8);
    // W1 [e][d][h] -> w1t [e][h][d]
    transpose_cvt<<<dim3(HIDDEN / 32, EMBED / 32, NEXP), tb, 0, stream>>>(
        W1, w1t, EMBED, HIDDEN, (size_t)EMBED * HIDDEN, (size_t)HIDDEN * EMBED, EMBED);
    // W2 [e][h][n] -> w2t [e][n][h]
    transpose_cvt<<<dim3(EMBED / 32, HIDDEN / 32, NEXP), tb, 0, stream>>>(
        W2, w2t, HIDDEN, EMBED, (size_t)HIDDEN * EMBED, (size_t)EMBED * HIDDEN, HIDDEN);

    router_kernel<<<TOKENS, 64, 0, stream>>>(x, Wr, br, rw);

    // gemm1: 4 M-chunks, R3-verbatim regime (grid bcol-fastest, chunk-contiguous hbuf)
    const size_t CHST = (size_t)NEXP * MC * HIDDEN;
    for (int c = 0; c < TOKENS / MC; ++c) {
        gemm1<<<dim3(HIDDEN / 128, MC / 128, NEXP), 256, 0, stream>>>(
            xb + (size_t)c * MC * EMBED, w1t, b1, rw + (size_t)c * MC * NEXP,
            hbuf + (size_t)c * CHST);
    }
    // gemm2: single dispatch, 256 blocks (1/CU), 2 experts per block
    gemm2<<<dim3(EMBED / 256, TOKENS / 256, 4), 512, 0, stream>>>(hbuf, w2t, b2, rw, out);
}

// Round 14
// 854.697 us; speedup vs baseline: 1.0541x; 1.0541x over previous
//
#include <hip/hip_runtime.h>
#include <hip/hip_bf16.h>
#include <cstdint>
#include <cstddef>

#define EMBED  1024
#define NEXP   8
#define HIDDEN 4096
#define TOKENS 4096

typedef __attribute__((ext_vector_type(8))) short bf16x8;
typedef __attribute__((ext_vector_type(4))) float f32x4;
using bf16 = __hip_bfloat16;

// ---------------- async global->LDS (16B per lane) ----------------
__device__ __forceinline__ void gload_lds16(const void* g, void* l) {
    __builtin_amdgcn_global_load_lds((const __attribute__((address_space(1))) void*)g,
                                     (__attribute__((address_space(3))) void*)l,
                                     16, 0, 0);
}

// LDS swizzles (involutions, both-sides per rule #21; 0 conflicts measured R5-R13):
__device__ __forceinline__ int swzA(int b) { return b ^ (((b >> 7) & 3) << 4); }  // [*][64B] tiles
__device__ __forceinline__ int swzB(int b) { return b ^ (((b >> 7) & 7) << 4); }  // [*][128B] tiles

// ---------------- fp32 -> bf16 elementwise convert ----------------
__global__ void cvt_kernel(const float* __restrict__ in, bf16* __restrict__ out, size_t n) {
    size_t i = ((size_t)blockIdx.x * blockDim.x + threadIdx.x) * 4;
    if (i + 3 < n) {
        float4 v = *(const float4*)(in + i);
        out[i + 0] = __float2bfloat16(v.x);
        out[i + 1] = __float2bfloat16(v.y);
        out[i + 2] = __float2bfloat16(v.z);
        out[i + 3] = __float2bfloat16(v.w);
    }
}

// ------------- transpose + convert: out[e][n][k] = in[e][k][n] -------------
__global__ void transpose_cvt(const float* __restrict__ in, bf16* __restrict__ out,
                              int K, int N, size_t in_estride, size_t out_eoff, int ldo) {
    const int e = blockIdx.z;
    const float* ine = in + (size_t)e * in_estride;
    bf16* oute = out + (size_t)e * out_eoff;
    __shared__ float tile[32][33];
    const int n0 = blockIdx.x * 32, k0 = blockIdx.y * 32;
    const int tx = threadIdx.x, ty = threadIdx.y;
    #pragma unroll
    for (int i = ty; i < 32; i += 8)
        tile[i][tx] = ine[(size_t)(k0 + i) * N + n0 + tx];
    __syncthreads();
    #pragma unroll
    for (int i = ty; i < 32; i += 8)
        oute[(size_t)(n0 + i) * ldo + k0 + tx] = __float2bfloat16(tile[tx][i]);
}

// ---------------- router: per-token top-2 masked softmax ----------------
__global__ void router_kernel(const float* __restrict__ x, const float* __restrict__ Wr,
                              const float* __restrict__ br, float* __restrict__ w) {
    const int t = blockIdx.x;
    const int lane = threadIdx.x;  // 64 threads
    const float* xt = x + (size_t)t * EMBED;
    float s[NEXP];
    #pragma unroll
    for (int e = 0; e < NEXP; e++) s[e] = 0.f;
    for (int k = lane; k < EMBED; k += 64) {
        const float xv = xt[k];
        const float* wrk = Wr + (size_t)k * NEXP;
        #pragma unroll
        for (int e = 0; e < NEXP; e++) s[e] = fmaf(xv, wrk[e], s[e]);
    }
    #pragma unroll
    for (int e = 0; e < NEXP; e++) {
        #pragma unroll
        for (int off = 32; off >= 1; off >>= 1)
            s[e] += __shfl_xor(s[e], off);
    }
    if (lane == 0) {
        float sc[NEXP];
        #pragma unroll
        for (int e = 0; e < NEXP; e++) sc[e] = s[e] + br[e];
        int i1 = 0; float m1 = sc[0];
        #pragma unroll
        for (int e = 1; e < NEXP; e++) if (sc[e] > m1) { m1 = sc[e]; i1 = e; }
        int i2 = -1; float m2 = -1e30f;
        #pragma unroll
        for (int e = 0; e < NEXP; e++) if (e != i1 && sc[e] > m2) { m2 = sc[e]; i2 = e; }
        const float mx = fmaxf(m1, 0.f);
        const float denom = 6.f * expf(0.f - mx) + expf(m1 - mx) + expf(m2 - mx);
        #pragma unroll
        for (int e = 0; e < NEXP; e++) {
            float v = (e == i1) ? m1 : ((e == i2) ? m2 : 0.f);
            w[(size_t)t * NEXP + e] = expf(v - mx) / denom;
        }
    }
}

// ============ GEMM1 (R9-verbatim): 128x128 3-slot ring + XCD-chunked e-outer decode ============
// LDS: 3 slots x (A 8KB + B 8KB) = 48KB -> 3 blocks/CU. Measured best gemm1: ~380 us.
#define G1_PREAMBLE(Abase, Bbase, lda, ldb)                                              \
    __shared__ __align__(16) bf16 As[3][128 * 32];                                       \
    __shared__ __align__(16) bf16 Bs[3][128 * 32];                                       \
    const int tid = threadIdx.x;                                                         \
    f32x4 acc[4][4] = {};                                                                \
    int srow[2], scol[2];                                                                \
    _Pragma("unroll")                                                                    \
    for (int j = 0; j < 2; j++) {                                                        \
        int b0 = tid * 16 + j * 4096;                                                    \
        int bs = swzA(b0);                                                               \
        srow[j] = bs >> 6; scol[j] = (bs & 63) >> 1;                                     \
    }                                                                                    \
    const bf16* ga0 = (Abase) + (size_t)(brow + srow[0]) * (lda) + scol[0];              \
    const bf16* ga1 = (Abase) + (size_t)(brow + srow[1]) * (lda) + scol[1];              \
    const bf16* gb0 = (Bbase) + (size_t)(bcol + srow[0]) * (ldb) + scol[0];              \
    const bf16* gb1 = (Bbase) + (size_t)(bcol + srow[1]) * (ldb) + scol[1];              \
    const int lane = tid & 63, wid = tid >> 6;                                           \
    const int wv_r = (wid >> 1) * 64, wv_c = (wid & 1) * 64;                             \
    const int fr = lane & 15, kbyte = (lane >> 4) * 16;                                  \
    int offA[4], offB[4];                                                                \
    _Pragma("unroll")                                                                    \
    for (int m = 0; m < 4; m++) {                                                        \
        offA[m] = swzA((wv_r + m * 16 + fr) * 64 + kbyte);                               \
        offB[m] = swzA((wv_c + m * 16 + fr) * 64 + kbyte);                               \
    }

#define G1_STAGE(s, kt)                                                                  \
    do {                                                                                 \
        gload_lds16(ga0 + (kt), &As[s][tid * 8]);                                        \
        gload_lds16(ga1 + (kt), &As[s][tid * 8 + 2048]);                                 \
        gload_lds16(gb0 + (kt), &Bs[s][tid * 8]);                                        \
        gload_lds16(gb1 + (kt), &Bs[s][tid * 8 + 2048]);                                 \
    } while (0)

#define G1_KLOOP(NT)                                                                     \
    G1_STAGE(0, 0);                                                                      \
    G1_STAGE(1, 32);                                                                     \
    {                                                                                    \
        int slot = 0, nslot = 2;                                                         \
        for (int t = 0; t < (NT); ++t) {                                                 \
            if (t + 2 < (NT)) { G1_STAGE(nslot, (t + 2) * 32); }                         \
            if (t < (NT) - 2)       asm volatile("s_waitcnt vmcnt(8)" ::: "memory");     \
            else if (t == (NT) - 2) asm volatile("s_waitcnt vmcnt(4)" ::: "memory");     \
            else                    asm volatile("s_waitcnt vmcnt(0)" ::: "memory");     \
            __builtin_amdgcn_s_barrier();                                                \
            __builtin_amdgcn_sched_barrier(0);                                           \
            const char* Ab = (const char*)As[slot];                                      \
            const char* Bb = (const char*)Bs[slot];                                      \
            bf16x8 af[4], bfr[4];                                                        \
            _Pragma("unroll")                                                            \
            for (int m = 0; m < 4; m++) af[m] = *(const bf16x8*)(Ab + offA[m]);          \
            _Pragma("unroll")                                                            \
            for (int n = 0; n < 4; n++) bfr[n] = *(const bf16x8*)(Bb + offB[n]);         \
            __builtin_amdgcn_s_setprio(1);                                               \
            _Pragma("unroll")                                                            \
            for (int m = 0; m < 4; m++)                                                  \
                _Pragma("unroll")                                                        \
                for (int n = 0; n < 4; n++)                                              \
                    acc[m][n] = __builtin_amdgcn_mfma_f32_16x16x32_bf16(af[m], bfr[n],   \
                                                                       acc[m][n], 0, 0, 0); \
            __builtin_amdgcn_s_setprio(0);                                               \
            asm volatile("" ::: "memory");                                               \
            __builtin_amdgcn_s_barrier();                                                \
            slot = (slot == 2) ? 0 : slot + 1;                                           \
            nslot = (nslot == 2) ? 0 : nslot + 1;                                        \
        }                                                                                \
    }

// h'[e][row][col] = w[t,e] * relu(x @ W1_e + b1_e)
// 1-D grid 8192; bijective XCD swizzle; e-outer: XCD k owns expert k
// (B working set 8MB disjoint per XCD; A-panel 256KB reused over 32 bcols from L2).
__global__ __launch_bounds__(256, 3) void gemm1(const bf16* __restrict__ A,   // x [4096][EMBED]
                                                const bf16* __restrict__ Bt,  // w1t [e][HIDDEN][EMBED]
                                                const float* __restrict__ b1,
                                                const float* __restrict__ rw,
                                                bf16* __restrict__ H) {
    const int wg = blockIdx.x;                    // 0..8191
    const int sw = (wg & 7) * 1024 + (wg >> 3);   // bijective chunked XCD swizzle
    const int e  = sw >> 10;                      // 0..7
    const int rem = sw & 1023;
    const int brow = (rem >> 5) * 128;            // brow outer
    const int bcol = (rem & 31) * 128;            // bcol inner
    const bf16* Be = Bt + (size_t)e * HIDDEN * EMBED;
    bf16* He = H + (size_t)e * TOKENS * HIDDEN;

    G1_PREAMBLE(A, Be, EMBED, EMBED)
    G1_KLOOP(EMBED / 32)

    #pragma unroll
    for (int n = 0; n < 4; n++) {
        const int col = bcol + wv_c + n * 16 + fr;
        const float bias = b1[e * HIDDEN + col];
        #pragma unroll
        for (int m = 0; m < 4; m++) {
            const int rowb = brow + wv_r + m * 16 + (lane >> 4) * 4;
            #pragma unroll
            for (int j = 0; j < 4; j++) {
                const int row = rowb + j;
                float v = acc[m][n][j] + bias;
                v = fmaxf(v, 0.f) * rw[(size_t)row * NEXP + e];
                He[(size_t)row * HIDDEN + col] = __float2bfloat16(v);
            }
        }
    }
}

// ======== GEMM2 (R12-verbatim): 256^2 8-wave rebalanced pipeline, 2 experts/block ========
// Grid (4, 16, 4) = 256 blocks = 1/CU. A layout [e][TOKENS][HIDDEN]. Measured ~381 us.
#define BARX()  { __builtin_amdgcn_sched_barrier(0); __builtin_amdgcn_s_barrier(); __builtin_amdgcn_sched_barrier(0); }
#define LGKM0() { asm volatile("s_waitcnt lgkmcnt(0)" ::: "memory"); __builtin_amdgcn_sched_barrier(0); }

// K-element offset of K-tile T (64 bf16 per tile), crossing into expert+1 at T=64:
#define KOFF(T, estride) ((size_t)((T) & 63) * 64 + (size_t)((T) >> 6) * (estride))

#define PIPE_PREAMBLE(Abase, Bbase, lda, ldb)                                        \
    __shared__ __align__(16) bf16 As[2][2][128 * 64];                                \
    __shared__ __align__(16) bf16 Bs[2][2][128 * 64];                                \
    const int tid = threadIdx.x;                                                     \
    const int lane = tid & 63, wid = tid >> 6;                                       \
    const int mhalf = wid >> 2, wB = wid & 3;                                        \
    const int nhalf = wB >> 1, nsub = wB & 1;                                        \
    const int wv_r = mhalf * 128, wv_c = wB * 64;                                    \
    f32x4 acc[8][4] = {};                                                            \
    int rowloc[2], colel[2];                                                         \
    _Pragma("unroll")                                                                \
    for (int j = 0; j < 2; j++) {                                                    \
        int bs = swzB(tid * 16 + j * 8192);                                          \
        rowloc[j] = bs >> 7; colel[j] = (bs & 127) >> 1;                             \
    }                                                                                \
    const bf16* pA0 = (Abase) + (size_t)(brow + rowloc[0]) * (lda) + colel[0];       \
    const bf16* pA1 = (Abase) + (size_t)(brow + rowloc[1]) * (lda) + colel[1];       \
    const bf16* pB0 = (Bbase) + (size_t)(bcol + rowloc[0]) * (ldb) + colel[0];       \
    const bf16* pB1 = (Bbase) + (size_t)(bcol + rowloc[1]) * (ldb) + colel[1];       \
    const int fr = lane & 15, kb0 = (lane >> 4) * 16;                                \
    const int xm = (fr & 7) << 4;                                                    \
    const int baA0 = (fr * 128 + kb0) ^ xm, baA1 = (fr * 128 + kb0 + 64) ^ xm;       \
    const int brB = (nsub * 64 + fr) * 128;                                          \
    const int baB0 = (brB + kb0) ^ xm, baB1 = (brB + kb0 + 64) ^ xm;

#define STAGE_A(bi, h, koff, lda)                                                    \
    do {                                                                             \
        gload_lds16(pA0 + (size_t)(h) * 128 * (lda) + (koff), &As[bi][h][tid * 8]);  \
        gload_lds16(pA1 + (size_t)(h) * 128 * (lda) + (koff), &As[bi][h][tid * 8 + 4096]); \
    } while (0)
#define STAGE_B(bi, h, koff, ldb)                                                    \
    do {                                                                             \
        gload_lds16(pB0 + (size_t)(h) * 128 * (ldb) + (koff), &Bs[bi][h][tid * 8]);  \
        gload_lds16(pB1 + (size_t)(h) * 128 * (ldb) + (koff), &Bs[bi][h][tid * 8 + 4096]); \
    } while (0)

#define MFMA_Q(mh, nh)                                                               \
    __builtin_amdgcn_s_setprio(1);                                                   \
    _Pragma("unroll")                                                                \
    for (int mm = 0; mm < 4; mm++)                                                   \
        _Pragma("unroll")                                                            \
        for (int nn = 0; nn < 2; nn++) {                                             \
            acc[(mh)*4+mm][(nh)*2+nn] = __builtin_amdgcn_mfma_f32_16x16x32_bf16(     \
                a[(mh)*4+mm][0], b[(nh)*2+nn][0], acc[(mh)*4+mm][(nh)*2+nn], 0,0,0); \
            acc[(mh)*4+mm][(nh)*2+nn] = __builtin_amdgcn_mfma_f32_16x16x32_bf16(     \
                a[(mh)*4+mm][1], b[(nh)*2+nn][1], acc[(mh)*4+mm][(nh)*2+nn], 0,0,0); \
        }                                                                            \
    __builtin_amdgcn_s_setprio(0);

#define PIPE_KLOOP(NT, lda, ldb, eA, eB)                                             \
    STAGE_A(0, 0, 0, lda); STAGE_A(0, 1, 0, lda);                                    \
    STAGE_B(0, 0, 0, ldb); STAGE_B(0, 1, 0, ldb);                                    \
    STAGE_A(1, 0, 64, lda); STAGE_A(1, 1, 64, lda);                                  \
    STAGE_B(1, 0, 64, ldb); STAGE_B(1, 1, 64, ldb);                                  \
    asm volatile("s_waitcnt vmcnt(8)" ::: "memory");                                 \
    BARX();                                                                          \
    for (int t = 0; t < (NT); ++t) {                                                 \
        const int bi = t & 1;                                                        \
        const bool st = (t + 2) < (NT);                                              \
        const size_t koffA = KOFF(t + 2, eA);                                        \
        const size_t koffB = KOFF(t + 2, eB);                                        \
        const char* Ah = (const char*)&As[bi][mhalf][0];                             \
        const char* Bh = (const char*)&Bs[bi][nhalf][0];                             \
        bf16x8 a[8][2], b[4][2];                                                     \
        /* PH1: read a0-3 (8) + b0-1 (4) -> Q(0,0) */                                \
        _Pragma("unroll")                                                            \
        for (int m = 0; m < 4; m++) {                                                \
            a[m][0] = *(const bf16x8*)(Ah + baA0 + m * 2048);                        \
            a[m][1] = *(const bf16x8*)(Ah + baA1 + m * 2048);                        \
        }                                                                            \
        _Pragma("unroll")                                                            \
        for (int n = 0; n < 2; n++) {                                                \
            b[n][0] = *(const bf16x8*)(Bh + baB0 + n * 2048);                        \
            b[n][1] = *(const bf16x8*)(Bh + baB1 + n * 2048);                        \
        }                                                                            \
        BARX(); LGKM0();                                                             \
        MFMA_Q(0, 0)                                                                 \
        /* PH2: read b2-3 (4) -> Q(0,1) */                                           \
        _Pragma("unroll")                                                            \
        for (int n = 2; n < 4; n++) {                                                \
            b[n][0] = *(const bf16x8*)(Bh + baB0 + n * 2048);                        \
            b[n][1] = *(const bf16x8*)(Bh + baB1 + n * 2048);                        \
        }                                                                            \
        BARX(); LGKM0();                                                             \
        MFMA_Q(0, 1)                                                                 \
        BARX();                                                                      \
        /* PH3: read a4-7 (8); stage B(t+2) -> Q(1,0) */                             \
        _Pragma("unroll")                                                            \
        for (int m = 4; m < 8; m++) {                                                \
            a[m][0] = *(const bf16x8*)(Ah + baA0 + m * 2048);                        \
            a[m][1] = *(const bf16x8*)(Ah + baA1 + m * 2048);                        \
        }                                                                            \
        if (st) { STAGE_B(bi, 0, koffB, ldb); STAGE_B(bi, 1, koffB, ldb); }          \
        BARX(); LGKM0();                                                             \
        MFMA_Q(1, 0)                                                                 \
        BARX();                                                                      \
        /* PH4: stage A(t+2); Q(1,1); counted vmcnt drains t+1 only */               \
        if (st) { STAGE_A(bi, 0, koffA, lda); STAGE_A(bi, 1, koffA, lda); }          \
        MFMA_Q(1, 1)                                                                 \
        if (st) { asm volatile("s_waitcnt vmcnt(8)" ::: "memory"); }                 \
        else    { asm volatile("s_waitcnt vmcnt(0)" ::: "memory"); }                 \
        BARX();                                                                      \
    }

// out = Sum_e h'_e @ W2_e (+ Sum_e w*b2). kc = expert pair {2kc, 2kc+1}.
__global__ __launch_bounds__(512, 2) void gemm2(const bf16* __restrict__ A,   // h' [NEXP][4096][HIDDEN]
                                                const bf16* __restrict__ Bt,  // w2t [e][EMBED][HIDDEN]
                                                const float* __restrict__ b2, // [NEXP][EMBED]
                                                const float* __restrict__ rw, // [M][8]
                                                float* __restrict__ out) {    // [M][EMBED]
    const int kc = blockIdx.z;            // 0..3 -> experts 2kc, 2kc+1
    const int brow = blockIdx.y * 256;
    const int bcol = blockIdx.x * 256;
    const size_t eA = (size_t)TOKENS * HIDDEN;   // expert stride in A
    const size_t eB = (size_t)EMBED * HIDDEN;    // expert stride in B
    const bf16* Ae = A + (size_t)(kc * 2) * eA;
    const bf16* Be = Bt + (size_t)(kc * 2) * eB;

    PIPE_PREAMBLE(Ae, Be, HIDDEN, HIDDEN)
    PIPE_KLOOP(128, HIDDEN, HIDDEN, eA, eB)

    #pragma unroll
    for (int n = 0; n < 4; n++) {
        const int col = bcol + wv_c + n * 16 + fr;
        #pragma unroll
        for (int m = 0; m < 8; m++) {
            const int rowb = brow + wv_r + m * 16 + (lane >> 4) * 4;
            #pragma unroll
            for (int j = 0; j < 4; j++) {
                const int row = rowb + j;
                float v = acc[m][n][j];
                if (kc == 0) {
                    const float* wrow = rw + (size_t)row * NEXP;
                    float s = 0.f;
                    #pragma unroll
                    for (int ee = 0; ee < NEXP; ee++) s = fmaf(wrow[ee], b2[ee * EMBED + col], s);
                    v += s;
                }
                atomicAdd(out + (size_t)row * EMBED + col, v);
            }
        }
    }
}

extern "C" void kernel_launch(void* const* d_in, const int* in_sizes, int n_in,
                              void* d_out, int out_size, void* d_ws, size_t ws_size,
                              hipStream_t stream) {
    const float* x  = (const float*)d_in[0];
    const float* W1 = (const float*)d_in[1];
    const float* b1 = (const float*)d_in[2];
    const float* W2 = (const float*)d_in[3];
    const float* b2 = (const float*)d_in[4];
    const float* Wr = (const float*)d_in[5];
    const float* br = (const float*)d_in[6];
    float* out = (float*)d_out;

    uint8_t* ws = (uint8_t*)d_ws;
    size_t off = 0;
    auto walloc = [&](size_t bytes) -> void* {
        void* p = ws + off;
        off += (bytes + 255) & ~(size_t)255;
        return p;
    };
    float* rw  = (float*)walloc((size_t)TOKENS * NEXP * 4);
    bf16* xb   = (bf16*)walloc((size_t)TOKENS * EMBED * 2);
    bf16* w1t  = (bf16*)walloc((size_t)NEXP * HIDDEN * EMBED * 2);
    bf16* w2t  = (bf16*)walloc((size_t)NEXP * EMBED * HIDDEN * 2);
    bf16* hbuf = (bf16*)walloc((size_t)NEXP * TOKENS * HIDDEN * 2);  // 256 MB, [e][4096][H]

    hipMemsetAsync(d_out, 0, (size_t)out_size * sizeof(float), stream);

    cvt_kernel<<<4096, 256, 0, stream>>>(x, xb, (size_t)TOKENS * EMBED);

    dim3 tb(32, 8);
    // W1 [e][d][h] -> w1t [e][h][d]
    transpose_cvt<<<dim3(HIDDEN / 32, EMBED / 32, NEXP), tb, 0, stream>>>(
        W1, w1t, EMBED, HIDDEN, (size_t)EMBED * HIDDEN, (size_t)HIDDEN * EMBED, EMBED);
    // W2 [e][h][n] -> w2t [e][n][h]
    transpose_cvt<<<dim3(EMBED / 32, HIDDEN / 32, NEXP), tb, 0, stream>>>(
        W2, w2t, HIDDEN, EMBED, (size_t)HIDDEN * EMBED, (size_t)EMBED * HIDDEN, HIDDEN);

    router_kernel<<<TOKENS, 64, 0, stream>>>(x, Wr, br, rw);

    // gemm1: R9-verbatim single dispatch (best measured: ~380 us)
    gemm1<<<8192, 256, 0, stream>>>(xb, w1t, b1, rw, hbuf);
    // gemm2: R12-verbatim single dispatch, 256 blocks (1/CU), 2 experts/block (~381 us)
    gemm2<<<dim3(EMBED / 256, TOKENS / 256, 4), 512, 0, stream>>>(hbuf, w2t, b2, rw, out);
}

// Round 15
// 801.799 us; speedup vs baseline: 1.1237x; 1.0660x over previous
//
#include <hip/hip_runtime.h>
#include <hip/hip_bf16.h>
#include <cstdint>
#include <cstddef>

#define EMBED  1024
#define NEXP   8
#define HIDDEN 4096
#define TOKENS 4096

typedef __attribute__((ext_vector_type(8))) short bf16x8;
typedef __attribute__((ext_vector_type(4))) float f32x4;
using bf16 = __hip_bfloat16;

// ---------------- async global->LDS (16B per lane) ----------------
__device__ __forceinline__ void gload_lds16(const void* g, void* l) {
    __builtin_amdgcn_global_load_lds((const __attribute__((address_space(1))) void*)g,
                                     (__attribute__((address_space(3))) void*)l,
                                     16, 0, 0);
}

// LDS swizzles (involutions, both-sides per rule #21; 0 conflicts measured R5-R14):
__device__ __forceinline__ int swzA(int b) { return b ^ (((b >> 7) & 3) << 4); }  // [*][64B] tiles
__device__ __forceinline__ int swzB(int b) { return b ^ (((b >> 7) & 7) << 4); }  // [*][128B] tiles

// ---------------- fp32 -> bf16 elementwise convert ----------------
__global__ void cvt_kernel(const float* __restrict__ in, bf16* __restrict__ out, size_t n) {
    size_t i = ((size_t)blockIdx.x * blockDim.x + threadIdx.x) * 4;
    if (i + 3 < n) {
        float4 v = *(const float4*)(in + i);
        out[i + 0] = __float2bfloat16(v.x);
        out[i + 1] = __float2bfloat16(v.y);
        out[i + 2] = __float2bfloat16(v.z);
        out[i + 3] = __float2bfloat16(v.w);
    }
}

// ------------- transpose + convert: out[e][n][k] = in[e][k][n] -------------
__global__ void transpose_cvt(const float* __restrict__ in, bf16* __restrict__ out,
                              int K, int N, size_t in_estride, size_t out_eoff, int ldo) {
    const int e = blockIdx.z;
    const float* ine = in + (size_t)e * in_estride;
    bf16* oute = out + (size_t)e * out_eoff;
    __shared__ float tile[32][33];
    const int n0 = blockIdx.x * 32, k0 = blockIdx.y * 32;
    const int tx = threadIdx.x, ty = threadIdx.y;
    #pragma unroll
    for (int i = ty; i < 32; i += 8)
        tile[i][tx] = ine[(size_t)(k0 + i) * N + n0 + tx];
    __syncthreads();
    #pragma unroll
    for (int i = ty; i < 32; i += 8)
        oute[(size_t)(n0 + i) * ldo + k0 + tx] = __float2bfloat16(tile[tx][i]);
}

// ---------------- router: per-token top-2 masked softmax ----------------
__global__ void router_kernel(const float* __restrict__ x, const float* __restrict__ Wr,
                              const float* __restrict__ br, float* __restrict__ w) {
    const int t = blockIdx.x;
    const int lane = threadIdx.x;  // 64 threads
    const float* xt = x + (size_t)t * EMBED;
    float s[NEXP];
    #pragma unroll
    for (int e = 0; e < NEXP; e++) s[e] = 0.f;
    for (int k = lane; k < EMBED; k += 64) {
        const float xv = xt[k];
        const float* wrk = Wr + (size_t)k * NEXP;
        #pragma unroll
        for (int e = 0; e < NEXP; e++) s[e] = fmaf(xv, wrk[e], s[e]);
    }
    #pragma unroll
    for (int e = 0; e < NEXP; e++) {
        #pragma unroll
        for (int off = 32; off >= 1; off >>= 1)
            s[e] += __shfl_xor(s[e], off);
    }
    if (lane == 0) {
        float sc[NEXP];
        #pragma unroll
        for (int e = 0; e < NEXP; e++) sc[e] = s[e] + br[e];
        int i1 = 0; float m1 = sc[0];
        #pragma unroll
        for (int e = 1; e < NEXP; e++) if (sc[e] > m1) { m1 = sc[e]; i1 = e; }
        int i2 = -1; float m2 = -1e30f;
        #pragma unroll
        for (int e = 0; e < NEXP; e++) if (e != i1 && sc[e] > m2) { m2 = sc[e]; i2 = e; }
        const float mx = fmaxf(m1, 0.f);
        const float denom = 6.f * expf(0.f - mx) + expf(m1 - mx) + expf(m2 - mx);
        #pragma unroll
        for (int e = 0; e < NEXP; e++) {
            float v = (e == i1) ? m1 : ((e == i2) ? m2 : 0.f);
            w[(size_t)t * NEXP + e] = expf(v - mx) / denom;
        }
    }
}

// ---------------- reduce: out = Sum_kc partials[kc] + Sum_e rw*b2 ----------------
// Grid: 4096 blocks (one row each) x 256 threads (4 cols each). Fully overwrites out.
__global__ __launch_bounds__(256) void reduce_kernel(const float* __restrict__ p,
                                                     const float* __restrict__ rw,
                                                     const float* __restrict__ b2,
                                                     float* __restrict__ out) {
    const int row = blockIdx.x;
    const int c4 = threadIdx.x * 4;
    const size_t S = (size_t)TOKENS * EMBED;
    const float* pr = p + (size_t)row * EMBED + c4;
    float4 v0 = *(const float4*)(pr);
    float4 v1 = *(const float4*)(pr + S);
    float4 v2 = *(const float4*)(pr + 2 * S);
    float4 v3 = *(const float4*)(pr + 3 * S);
    float4 v;
    v.x = v0.x + v1.x + v2.x + v3.x;
    v.y = v0.y + v1.y + v2.y + v3.y;
    v.z = v0.z + v1.z + v2.z + v3.z;
    v.w = v0.w + v1.w + v2.w + v3.w;
    const float* wrow = rw + (size_t)row * NEXP;
    #pragma unroll
    for (int e = 0; e < NEXP; e++) {
        const float we = wrow[e];
        float4 bb = *(const float4*)(b2 + (size_t)e * EMBED + c4);
        v.x = fmaf(we, bb.x, v.x);
        v.y = fmaf(we, bb.y, v.y);
        v.z = fmaf(we, bb.z, v.z);
        v.w = fmaf(we, bb.w, v.w);
    }
    *(float4*)(out + (size_t)row * EMBED + c4) = v;
}

// ============ GEMM1 (R9-verbatim): 128x128 3-slot ring + XCD-chunked e-outer decode ============
#define G1_PREAMBLE(Abase, Bbase, lda, ldb)                                              \
    __shared__ __align__(16) bf16 As[3][128 * 32];                                       \
    __shared__ __align__(16) bf16 Bs[3][128 * 32];                                       \
    const int tid = threadIdx.x;                                                         \
    f32x4 acc[4][4] = {};                                                                \
    int srow[2], scol[2];                                                                \
    _Pragma("unroll")                                                                    \
    for (int j = 0; j < 2; j++) {                                                        \
        int b0 = tid * 16 + j * 4096;                                                    \
        int bs = swzA(b0);                                                               \
        srow[j] = bs >> 6; scol[j] = (bs & 63) >> 1;                                     \
    }                                                                                    \
    const bf16* ga0 = (Abase) + (size_t)(brow + srow[0]) * (lda) + scol[0];              \
    const bf16* ga1 = (Abase) + (size_t)(brow + srow[1]) * (lda) + scol[1];              \
    const bf16* gb0 = (Bbase) + (size_t)(bcol + srow[0]) * (ldb) + scol[0];              \
    const bf16* gb1 = (Bbase) + (size_t)(bcol + srow[1]) * (ldb) + scol[1];              \
    const int lane = tid & 63, wid = tid >> 6;                                           \
    const int wv_r = (wid >> 1) * 64, wv_c = (wid & 1) * 64;                             \
    const int fr = lane & 15, kbyte = (lane >> 4) * 16;                                  \
    int offA[4], offB[4];                                                                \
    _Pragma("unroll")                                                                    \
    for (int m = 0; m < 4; m++) {                                                        \
        offA[m] = swzA((wv_r + m * 16 + fr) * 64 + kbyte);                               \
        offB[m] = swzA((wv_c + m * 16 + fr) * 64 + kbyte);                               \
    }

#define G1_STAGE(s, kt)                                                                  \
    do {                                                                                 \
        gload_lds16(ga0 + (kt), &As[s][tid * 8]);                                        \
        gload_lds16(ga1 + (kt), &As[s][tid * 8 + 2048]);                                 \
        gload_lds16(gb0 + (kt), &Bs[s][tid * 8]);                                        \
        gload_lds16(gb1 + (kt), &Bs[s][tid * 8 + 2048]);                                 \
    } while (0)

#define G1_KLOOP(NT)                                                                     \
    G1_STAGE(0, 0);                                                                      \
    G1_STAGE(1, 32);                                                                     \
    {                                                                                    \
        int slot = 0, nslot = 2;                                                         \
        for (int t = 0; t < (NT); ++t) {                                                 \
            if (t + 2 < (NT)) { G1_STAGE(nslot, (t + 2) * 32); }                         \
            if (t < (NT) - 2)       asm volatile("s_waitcnt vmcnt(8)" ::: "memory");     \
            else if (t == (NT) - 2) asm volatile("s_waitcnt vmcnt(4)" ::: "memory");     \
            else                    asm volatile("s_waitcnt vmcnt(0)" ::: "memory");     \
            __builtin_amdgcn_s_barrier();                                                \
            __builtin_amdgcn_sched_barrier(0);                                           \
            const char* Ab = (const char*)As[slot];                                      \
            const char* Bb = (const char*)Bs[slot];                                      \
            bf16x8 af[4], bfr[4];                                                        \
            _Pragma("unroll")                                                            \
            for (int m = 0; m < 4; m++) af[m] = *(const bf16x8*)(Ab + offA[m]);          \
            _Pragma("unroll")                                                            \
            for (int n = 0; n < 4; n++) bfr[n] = *(const bf16x8*)(Bb + offB[n]);         \
            __builtin_amdgcn_s_setprio(1);                                               \
            _Pragma("unroll")                                                            \
            for (int m = 0; m < 4; m++)                                                  \
                _Pragma("unroll")                                                        \
                for (int n = 0; n < 4; n++)                                              \
                    acc[m][n] = __builtin_amdgcn_mfma_f32_16x16x32_bf16(af[m], bfr[n],   \
                                                                       acc[m][n], 0, 0, 0); \
            __builtin_amdgcn_s_setprio(0);                                               \
            asm volatile("" ::: "memory");                                               \
            __builtin_amdgcn_s_barrier();                                                \
            slot = (slot == 2) ? 0 : slot + 1;                                           \
            nslot = (nslot == 2) ? 0 : nslot + 1;                                        \
        }                                                                                \
    }

__global__ __launch_bounds__(256, 3) void gemm1(const bf16* __restrict__ A,   // x [4096][EMBED]
                                                const bf16* __restrict__ Bt,  // w1t [e][HIDDEN][EMBED]
                                                const float* __restrict__ b1,
                                                const float* __restrict__ rw,
                                                bf16* __restrict__ H) {
    const int wg = blockIdx.x;                    // 0..8191
    const int sw = (wg & 7) * 1024 + (wg >> 3);   // bijective chunked XCD swizzle
    const int e  = sw >> 10;                      // 0..7
    const int rem = sw & 1023;
    const int brow = (rem >> 5) * 128;            // brow outer
    const int bcol = (rem & 31) * 128;            // bcol inner
    const bf16* Be = Bt + (size_t)e * HIDDEN * EMBED;
    bf16* He = H + (size_t)e * TOKENS * HIDDEN;

    G1_PREAMBLE(A, Be, EMBED, EMBED)
    G1_KLOOP(EMBED / 32)

    #pragma unroll
    for (int n = 0; n < 4; n++) {
        const int col = bcol + wv_c + n * 16 + fr;
        const float bias = b1[e * HIDDEN + col];
        #pragma unroll
        for (int m = 0; m < 4; m++) {
            const int rowb = brow + wv_r + m * 16 + (lane >> 4) * 4;
            #pragma unroll
            for (int j = 0; j < 4; j++) {
                const int row = rowb + j;
                float v = acc[m][n][j] + bias;
                v = fmaxf(v, 0.f) * rw[(size_t)row * NEXP + e];
                He[(size_t)row * HIDDEN + col] = __float2bfloat16(v);
            }
        }
    }
}

// ======== GEMM2 (R12 pipe): 256^2 8-wave rebalanced pipeline, 2 experts/block ========
// Grid (4, 16, 4) = 256 blocks = 1/CU. Epilogue: plain stores to private partials[kc].
#define BARX()  { __builtin_amdgcn_sched_barrier(0); __builtin_amdgcn_s_barrier(); __builtin_amdgcn_sched_barrier(0); }
#define LGKM0() { asm volatile("s_waitcnt lgkmcnt(0)" ::: "memory"); __builtin_amdgcn_sched_barrier(0); }

// K-element offset of K-tile T (64 bf16 per tile), crossing into expert+1 at T=64:
#define KOFF(T, estride) ((size_t)((T) & 63) * 64 + (size_t)((T) >> 6) * (estride))

#define PIPE_PREAMBLE(Abase, Bbase, lda, ldb)                                        \
    __shared__ __align__(16) bf16 As[2][2][128 * 64];                                \
    __shared__ __align__(16) bf16 Bs[2][2][128 * 64];                                \
    const int tid = threadIdx.x;                                                     \
    const int lane = tid & 63, wid = tid >> 6;                                       \
    const int mhalf = wid >> 2, wB = wid & 3;                                        \
    const int nhalf = wB >> 1, nsub = wB & 1;                                        \
    const int wv_r = mhalf * 128, wv_c = wB * 64;                                    \
    f32x4 acc[8][4] = {};                                                            \
    int rowloc[2], colel[2];                                                         \
    _Pragma("unroll")                                                                \
    for (int j = 0; j < 2; j++) {                                                    \
        int bs = swzB(tid * 16 + j * 8192);                                          \
        rowloc[j] = bs >> 7; colel[j] = (bs & 127) >> 1;                             \
    }                                                                                \
    const bf16* pA0 = (Abase) + (size_t)(brow + rowloc[0]) * (lda) + colel[0];       \
    const bf16* pA1 = (Abase) + (size_t)(brow + rowloc[1]) * (lda) + colel[1];       \
    const bf16* pB0 = (Bbase) + (size_t)(bcol + rowloc[0]) * (ldb) + colel[0];       \
    const bf16* pB1 = (Bbase) + (size_t)(bcol + rowloc[1]) * (ldb) + colel[1];       \
    const int fr = lane & 15, kb0 = (lane >> 4) * 16;                                \
    const int xm = (fr & 7) << 4;                                                    \
    const int baA0 = (fr * 128 + kb0) ^ xm, baA1 = (fr * 128 + kb0 + 64) ^ xm;       \
    const int brB = (nsub * 64 + fr) * 128;                                          \
    const int baB0 = (brB + kb0) ^ xm, baB1 = (brB + kb0 + 64) ^ xm;

#define STAGE_A(bi, h, koff, lda)                                                    \
    do {                                                                             \
        gload_lds16(pA0 + (size_t)(h) * 128 * (lda) + (koff), &As[bi][h][tid * 8]);  \
        gload_lds16(pA1 + (size_t)(h) * 128 * (lda) + (koff), &As[bi][h][tid * 8 + 4096]); \
    } while (0)
#define STAGE_B(bi, h, koff, ldb)                                                    \
    do {                                                                             \
        gload_lds16(pB0 + (size_t)(h) * 128 * (ldb) + (koff), &Bs[bi][h][tid * 8]);  \
        gload_lds16(pB1 + (size_t)(h) * 128 * (ldb) + (koff), &Bs[bi][h][tid * 8 + 4096]); \
    } while (0)

#define MFMA_Q(mh, nh)                                                               \
    __builtin_amdgcn_s_setprio(1);                                                   \
    _Pragma("unroll")                                                                \
    for (int mm = 0; mm < 4; mm++)                                                   \
        _Pragma("unroll")                                                            \
        for (int nn = 0; nn < 2; nn++) {                                             \
            acc[(mh)*4+mm][(nh)*2+nn] = __builtin_amdgcn_mfma_f32_16x16x32_bf16(     \
                a[(mh)*4+mm][0], b[(nh)*2+nn][0], acc[(mh)*4+mm][(nh)*2+nn], 0,0,0); \
            acc[(mh)*4+mm][(nh)*2+nn] = __builtin_amdgcn_mfma_f32_16x16x32_bf16(     \
                a[(mh)*4+mm][1], b[(nh)*2+nn][1], acc[(mh)*4+mm][(nh)*2+nn], 0,0,0); \
        }                                                                            \
    __builtin_amdgcn_s_setprio(0);

#define PIPE_KLOOP(NT, lda, ldb, eA, eB)                                             \
    STAGE_A(0, 0, 0, lda); STAGE_A(0, 1, 0, lda);                                    \
    STAGE_B(0, 0, 0, ldb); STAGE_B(0, 1, 0, ldb);                                    \
    STAGE_A(1, 0, 64, lda); STAGE_A(1, 1, 64, lda);                                  \
    STAGE_B(1, 0, 64, ldb); STAGE_B(1, 1, 64, ldb);                                  \
    asm volatile("s_waitcnt vmcnt(8)" ::: "memory");                                 \
    BARX();                                                                          \
    for (int t = 0; t < (NT); ++t) {                                                 \
        const int bi = t & 1;                                                        \
        const bool st = (t + 2) < (NT);                                              \
        const size_t koffA = KOFF(t + 2, eA);                                        \
        const size_t koffB = KOFF(t + 2, eB);                                        \
        const char* Ah = (const char*)&As[bi][mhalf][0];                             \
        const char* Bh = (const char*)&Bs[bi][nhalf][0];                             \
        bf16x8 a[8][2], b[4][2];                                                     \
        /* PH1: read a0-3 (8) + b0-1 (4) -> Q(0,0) */                                \
        _Pragma("unroll")                                                            \
        for (int m = 0; m < 4; m++) {                                                \
            a[m][0] = *(const bf16x8*)(Ah + baA0 + m * 2048);                        \
            a[m][1] = *(const bf16x8*)(Ah + baA1 + m * 2048);                        \
        }                                                                            \
        _Pragma("unroll")                                                            \
        for (int n = 0; n < 2; n++) {                                                \
            b[n][0] = *(const bf16x8*)(Bh + baB0 + n * 2048);                        \
            b[n][1] = *(const bf16x8*)(Bh + baB1 + n * 2048);                        \
        }                                                                            \
        BARX(); LGKM0();                                                             \
        MFMA_Q(0, 0)                                                                 \
        /* PH2: read b2-3 (4) -> Q(0,1) */                                           \
        _Pragma("unroll")                                                            \
        for (int n = 2; n < 4; n++) {                                                \
            b[n][0] = *(const bf16x8*)(Bh + baB0 + n * 2048);                        \
            b[n][1] = *(const bf16x8*)(Bh + baB1 + n * 2048);                        \
        }                                                                            \
        BARX(); LGKM0();                                                             \
        MFMA_Q(0, 1)                                                                 \
        BARX();                                                                      \
        /* PH3: read a4-7 (8); stage B(t+2) -> Q(1,0) */                             \
        _Pragma("unroll")                                                            \
        for (int m = 4; m < 8; m++) {                                                \
            a[m][0] = *(const bf16x8*)(Ah + baA0 + m * 2048);                        \
            a[m][1] = *(const bf16x8*)(Ah + baA1 + m * 2048);                        \
        }                                                                            \
        if (st) { STAGE_B(bi, 0, koffB, ldb); STAGE_B(bi, 1, koffB, ldb); }          \
        BARX(); LGKM0();                                                             \
        MFMA_Q(1, 0)                                                                 \
        BARX();                                                                      \
        /* PH4: stage A(t+2); Q(1,1); counted vmcnt drains t+1 only */               \
        if (st) { STAGE_A(bi, 0, koffA, lda); STAGE_A(bi, 1, koffA, lda); }          \
        MFMA_Q(1, 1)                                                                 \
        if (st) { asm volatile("s_waitcnt vmcnt(8)" ::: "memory"); }                 \
        else    { asm volatile("s_waitcnt vmcnt(0)" ::: "memory"); }                 \
        BARX();                                                                      \
    }

// partials[kc] = h'_{2kc} @ W2_{2kc} + h'_{2kc+1} @ W2_{2kc+1}  (plain stores, no atomics)
__global__ __launch_bounds__(512, 2) void gemm2(const bf16* __restrict__ A,   // h' [NEXP][4096][HIDDEN]
                                                const bf16* __restrict__ Bt,  // w2t [e][EMBED][HIDDEN]
                                                float* __restrict__ partials) { // [4][4096][EMBED]
    const int kc = blockIdx.z;            // 0..3 -> experts 2kc, 2kc+1
    const int brow = blockIdx.y * 256;
    const int bcol = blockIdx.x * 256;
    const size_t eA = (size_t)TOKENS * HIDDEN;   // expert stride in A
    const size_t eB = (size_t)EMBED * HIDDEN;    // expert stride in B
    const bf16* Ae = A + (size_t)(kc * 2) * eA;
    const bf16* Be = Bt + (size_t)(kc * 2) * eB;
    float* pout = partials + (size_t)kc * TOKENS * EMBED;

    PIPE_PREAMBLE(Ae, Be, HIDDEN, HIDDEN)
    PIPE_KLOOP(128, HIDDEN, HIDDEN, eA, eB)

    #pragma unroll
    for (int n = 0; n < 4; n++) {
        const int col = bcol + wv_c + n * 16 + fr;
        #pragma unroll
        for (int m = 0; m < 8; m++) {
            const int rowb = brow + wv_r + m * 16 + (lane >> 4) * 4;
            #pragma unroll
            for (int j = 0; j < 4; j++) {
                const int row = rowb + j;
                pout[(size_t)row * EMBED + col] = acc[m][n][j];
            }
        }
    }
}

extern "C" void kernel_launch(void* const* d_in, const int* in_sizes, int n_in,
                              void* d_out, int out_size, void* d_ws, size_t ws_size,
                              hipStream_t stream) {
    const float* x  = (const float*)d_in[0];
    const float* W1 = (const float*)d_in[1];
    const float* b1 = (const float*)d_in[2];
    const float* W2 = (const float*)d_in[3];
    const float* b2 = (const float*)d_in[4];
    const float* Wr = (const float*)d_in[5];
    const float* br = (const float*)d_in[6];
    float* out = (float*)d_out;

    uint8_t* ws = (uint8_t*)d_ws;
    size_t off = 0;
    auto walloc = [&](size_t bytes) -> void* {
        void* p = ws + off;
        off += (bytes + 255) & ~(size_t)255;
        return p;
    };
    float* rw  = (float*)walloc((size_t)TOKENS * NEXP * 4);
    bf16* xb   = (bf16*)walloc((size_t)TOKENS * EMBED * 2);
    bf16* w1t  = (bf16*)walloc((size_t)NEXP * HIDDEN * EMBED * 2);   // 64 MB
    bf16* w2t  = (bf16*)walloc((size_t)NEXP * EMBED * HIDDEN * 2);   // 64 MB
    bf16* hbuf = (bf16*)walloc((size_t)NEXP * TOKENS * HIDDEN * 2);  // 256 MB
    // partials (4 x 16 MB fp32 = 64 MB) aliases w1t: w1t is dead once gemm1 completes,
    // and stream order guarantees gemm1 < gemm2 < reduce. Rewritten fully every launch.
    float* partials = (float*)w1t;

    cvt_kernel<<<4096, 256, 0, stream>>>(x, xb, (size_t)TOKENS * EMBED);

    dim3 tb(32, 8);
    // W1 [e][d][h] -> w1t [e][h][d]
    transpose_cvt<<<dim3(HIDDEN / 32, EMBED / 32, NEXP), tb, 0, stream>>>(
        W1, w1t, EMBED, HIDDEN, (size_t)EMBED * HIDDEN, (size_t)HIDDEN * EMBED, EMBED);
    // W2 [e][h][n] -> w2t [e][n][h]
    transpose_cvt<<<dim3(EMBED / 32, HIDDEN / 32, NEXP), tb, 0, stream>>>(
        W2, w2t, HIDDEN, EMBED, (size_t)HIDDEN * EMBED, (size_t)EMBED * HIDDEN, HIDDEN);

    router_kernel<<<TOKENS, 64, 0, stream>>>(x, Wr, br, rw);

    // gemm1: R9-verbatim single dispatch (~380-400 us)
    gemm1<<<8192, 256, 0, stream>>>(xb, w1t, b1, rw, hbuf);
    // gemm2: single dispatch, 256 blocks (1/CU), 2 experts/block, atomic-free stores
    gemm2<<<dim3(EMBED / 256, TOKENS / 256, 4), 512, 0, stream>>>(hbuf, w2t, partials);
    // reduce: sum 4 partial slices + router-weighted b2 bias -> out (fully overwrites)
    reduce_kernel<<<TOKENS, 256, 0, stream>>>(partials, rw, b2, out);
}